// Round 8
// baseline (167.692 us; speedup 1.0000x reference)
//
#include <hip/hip_runtime.h>
#include <hip/hip_bf16.h>

typedef unsigned short u16;
typedef unsigned int u32;
typedef unsigned long long u64;
typedef __bf16 bf16x8 __attribute__((ext_vector_type(8)));
typedef unsigned short u16x8 __attribute__((ext_vector_type(8)));
typedef float f32x16 __attribute__((ext_vector_type(16)));
typedef float f32x4 __attribute__((ext_vector_type(4)));

#define TEMP_INV (1.0f / 0.07f)
#define LOG2E 1.4426950408889634f
#define SC_A  1099511627776.0f        // 2^40 (power of 2: f32 multiply exact)
#define ISC_A 9.094947017729282e-13   // 2^-40
#define SC_Z  1125899906842624.0f     // 2^50
#define ISC_Z 8.881784197001252e-16   // 2^-50

#if __has_builtin(__builtin_amdgcn_exp2f)
#define EXP2(x) __builtin_amdgcn_exp2f(x)
#else
#define EXP2(x) exp2f(x)
#endif

#define N_Z 524288      // 4096*128

// ---- workspace layout (4.74 MB) ----
// cb: bf16 z|spr|f|zmix (4 MB, written by prep convert)
// Rfp[8][4096] | Rsp[8][4096] f32 partial pool maxes (plain stores)
// PA u64[4][4096] (Az,Ax i64*2^40; Zz,Zx u64*2^50)  -- zeroed by prep
// CNT u32[4096]  ((2*wsum)<<16 | ones)              -- zeroed by prep
// accum f32 + ticket u32 + pad                       -- zeroed by prep
// mnbBits[256][128] u32 (fully rewritten each iter)
#define CB_OFF   0
#define RF_OFF   4194304
#define RS_OFF   4325376
#define PACC_OFF 4456448
#define CNT_OFF  4587520
#define AT_OFF   4603904
#define MNB_OFF  4603920
#define ZERO_UNITS 9217   // (PA 131072 + CNT 16384 + AT 16) / 16

// k_prep block ranges
#define PM_BLKS 256
#define CONV0 PM_BLKS                   // 256
#define CONV_BLKS 2048
#define MNB0 (CONV0 + CONV_BLKS)        // 2304
#define MNB_BLKS 256
#define ZERO0 (MNB0 + MNB_BLKS)         // 2560
#define ZERO_BLKS 37
#define PREP_BLKS (ZERO0 + ZERO_BLKS)   // 2597

// LDS tile for prep poolmax only
#define TSTRIDE 136
#define TMAT 4352   // 32*136 u16 per mat

// load 8 f32, convert to bf16x8 (RNE — matches the convert path bit-exactly)
__device__ __forceinline__ bf16x8 ldcvt8(const float* __restrict__ p) {
    f32x4 a = *(const f32x4*)p;
    f32x4 b = *(const f32x4*)(p + 4);
    u16x8 t;
    t[0] = __bfloat16_as_ushort(__float2bfloat16(a[0]));
    t[1] = __bfloat16_as_ushort(__float2bfloat16(a[1]));
    t[2] = __bfloat16_as_ushort(__float2bfloat16(a[2]));
    t[3] = __bfloat16_as_ushort(__float2bfloat16(a[3]));
    t[4] = __bfloat16_as_ushort(__float2bfloat16(b[0]));
    t[5] = __bfloat16_as_ushort(__float2bfloat16(b[1]));
    t[6] = __bfloat16_as_ushort(__float2bfloat16(b[2]));
    t[7] = __bfloat16_as_ushort(__float2bfloat16(b[3]));
    return __builtin_bit_cast(bf16x8, t);
}

// global fragment load: row-major [.,128] bf16, 16B at (row, koff)
__device__ __forceinline__ bf16x8 ldfrag(const u16* __restrict__ base, int row, int koff) {
    return *(const bf16x8*)(base + (size_t)row * 128 + koff);
}

// ---------------- Kernel 0: prep ----------------
// [0,256): pool partial maxes (f32 inputs, inline cvt, plain partial stores)
// [256,2304): f32->bf16 convert of z,spr,f,zmix into cb
// [2304,2560): mnb bit-pack (1 row per block)
// [2560,2597): zero PA/CNT/accum/ticket
__global__ __launch_bounds__(256) void k_prep(
    const float* __restrict__ z, const float* __restrict__ spr,
    const float* __restrict__ f, const float* __restrict__ pag,
    const float* __restrict__ psp, const float* __restrict__ zmx,
    const float* __restrict__ mnb,
    u16* __restrict__ cb, u32* __restrict__ mnbBits,
    float* __restrict__ Rfp, float* __restrict__ Rsp, u64* __restrict__ PA) {
    __shared__ u16 stile[2][2 * TMAT];
    int b = blockIdx.x;
    int tid = threadIdx.x;

    if (b < PM_BLKS) {
        int x = b & 31, y = b >> 5;
        int lane = tid & 63, w = tid >> 6;
        int half = lane >> 5, li = lane & 31;
        int i = x * 128 + w * 32 + li;
        int pybase = y * 128;
        int srow = tid >> 4, sc16 = tid & 15;

        bf16x8 brf[8], brs[8];
#pragma unroll
        for (int kc = 0; kc < 8; ++kc) {
            int koff = kc * 16 + half * 8;
            brf[kc] = ldcvt8(f + (size_t)i * 128 + koff);
            brs[kc] = ldcvt8(spr + (size_t)i * 128 + koff);
        }

        bf16x8 q00, q01, q10, q11;
        {   // tile 0 -> buf0
            const float* pr = pag + (size_t)(pybase + srow) * 128 + sc16 * 8;
            const float* ps = psp + (size_t)(pybase + srow) * 128 + sc16 * 8;
            q00 = ldcvt8(pr); q01 = ldcvt8(pr + 16 * 128);
            q10 = ldcvt8(ps); q11 = ldcvt8(ps + 16 * 128);
            u16* tb = stile[0];
            *(bf16x8*)(tb + (size_t)srow * TSTRIDE + sc16 * 8) = q00;
            *(bf16x8*)(tb + (size_t)(srow + 16) * TSTRIDE + sc16 * 8) = q01;
            *(bf16x8*)(tb + TMAT + (size_t)srow * TSTRIDE + sc16 * 8) = q10;
            *(bf16x8*)(tb + TMAT + (size_t)(srow + 16) * TSTRIDE + sc16 * 8) = q11;
        }
        {   // prefetch tile 1
            const float* pr = pag + (size_t)(pybase + 32 + srow) * 128 + sc16 * 8;
            const float* ps = psp + (size_t)(pybase + 32 + srow) * 128 + sc16 * 8;
            q00 = ldcvt8(pr); q01 = ldcvt8(pr + 16 * 128);
            q10 = ldcvt8(ps); q11 = ldcvt8(ps + 16 * 128);
        }

        float rmf = -1e30f, rms = -1e30f;
#pragma unroll
        for (int t = 0; t < 4; ++t) {
            __syncthreads();
            if (t < 3) {
                u16* tb = stile[(t + 1) & 1];
                *(bf16x8*)(tb + (size_t)srow * TSTRIDE + sc16 * 8) = q00;
                *(bf16x8*)(tb + (size_t)(srow + 16) * TSTRIDE + sc16 * 8) = q01;
                *(bf16x8*)(tb + TMAT + (size_t)srow * TSTRIDE + sc16 * 8) = q10;
                *(bf16x8*)(tb + TMAT + (size_t)(srow + 16) * TSTRIDE + sc16 * 8) = q11;
                if (t < 2) {
                    const float* pr = pag + (size_t)(pybase + (t + 2) * 32 + srow) * 128 + sc16 * 8;
                    const float* ps = psp + (size_t)(pybase + (t + 2) * 32 + srow) * 128 + sc16 * 8;
                    q00 = ldcvt8(pr); q01 = ldcvt8(pr + 16 * 128);
                    q10 = ldcvt8(ps); q11 = ldcvt8(ps + 16 * 128);
                }
            }
            const u16* tb = stile[t & 1];
            f32x16 accf = {}; f32x16 accs = {};
            __builtin_amdgcn_s_setprio(1);
#pragma unroll
            for (int kc = 0; kc < 8; ++kc) {
                const u16* ab = tb + li * TSTRIDE + kc * 16 + half * 8;
                bf16x8 a0 = *(const bf16x8*)ab;
                bf16x8 a1 = *(const bf16x8*)(ab + TMAT);
                accf = __builtin_amdgcn_mfma_f32_32x32x16_bf16(a0, brf[kc], accf, 0, 0, 0);
                accs = __builtin_amdgcn_mfma_f32_32x32x16_bf16(a1, brs[kc], accs, 0, 0, 0);
            }
            __builtin_amdgcn_s_setprio(0);
#pragma unroll
            for (int r = 0; r < 16; ++r) {
                rmf = fmaxf(rmf, accf[r]);
                rms = fmaxf(rms, accs[r]);
            }
        }
        rmf = fmaxf(rmf, __shfl_xor(rmf, 32, 64));
        rms = fmaxf(rms, __shfl_xor(rms, 32, 64));
        if (half == 0) {
            Rfp[(size_t)y * 4096 + i] = rmf;
            Rsp[(size_t)y * 4096 + i] = rms;
        }
        return;
    }
    if (b < MNB0) {
        // convert z,spr,f,zmix f32->bf16 into cb (4 * 524288 contiguous elems)
        size_t e0 = ((size_t)(b - CONV0) * 256 + tid) * 4;
        const float* src; size_t off;
        if (e0 < N_Z)          { src = z;   off = e0; }
        else if (e0 < 2 * N_Z) { src = spr; off = e0 - N_Z; }
        else if (e0 < 3 * N_Z) { src = f;   off = e0 - 2 * N_Z; }
        else                   { src = zmx; off = e0 - 3 * N_Z; }
        f32x4 v = *(const f32x4*)(src + off);
        ushort4 o;
        o.x = __bfloat16_as_ushort(__float2bfloat16(v[0]));
        o.y = __bfloat16_as_ushort(__float2bfloat16(v[1]));
        o.z = __bfloat16_as_ushort(__float2bfloat16(v[2]));
        o.w = __bfloat16_as_ushort(__float2bfloat16(v[3]));
        *(ushort4*)(cb + e0) = o;
        return;
    }
    if (b < ZERO0) {
        // pack mnb row: [4096] f32 -> 64 u64 words; bit l of word w <-> j = w*64+l
        int row = b - MNB0;
        int wv = tid >> 6, l = tid & 63;
        const float* srcm = mnb + (size_t)row * 4096;
        u64* db = (u64*)mnbBits + ((size_t)row << 6);
#pragma unroll
        for (int t = 0; t < 16; ++t) {
            int word = wv * 16 + t;
            u64 m = __ballot(srcm[word * 64 + l] > 0.0f);
            if (l == t) db[word] = m;
        }
        return;
    }
    {   // zero PA / CNT / accum / ticket
        int u = (b - ZERO0) * 256 + tid;
        if (u < ZERO_UNITS) {
            uint4 zero = {0, 0, 0, 0};
            *(uint4*)((char*)PA + (size_t)u * 16) = zero;
        }
    }
}

// ---------------- Kernel 1: main fused two-pass kernel (NO LDS tiles, NO barriers) ----------------
// grid (32, 32): 128 i per block, 128-j chunk. The 4 bf16 feature mats total 4 MB ->
// fit per-XCD L2 (and phase j-tile 16 KB fits L1), so MFMA A-fragments are loaded
// DIRECTLY from global (identical values the LDS tile held). Waves run unsynced
// after one initial barrier -> wave drift + setprio hide latency.
__global__ __launch_bounds__(256) void k_main(
    const u16* __restrict__ cb, const u32* __restrict__ mnbBits,
    const float* __restrict__ Rfp, const float* __restrict__ Rsp,
    u64* __restrict__ PA, u32* __restrict__ CNT) {
    __shared__ float sRf[128], sRs[128];

    const u16* zb   = cb;
    const u16* sprb = cb + N_Z;
    const u16* fb   = cb + 2 * N_Z;
    const u16* zmxb = cb + 3 * N_Z;

    int tid = threadIdx.x;
    int lane = tid & 63, w = tid >> 6;
    int half = lane >> 5, li = lane & 31;
    int i = blockIdx.x * 128 + w * 32 + li;
    int cbase = blockIdx.y * 128;

    // chunk's pool maxes: 8-way partial max into LDS (broadcast reads later)
    if (tid < 128) {
        float m = Rfp[cbase + tid];
#pragma unroll
        for (int y = 1; y < 8; ++y) m = fmaxf(m, Rfp[(size_t)y * 4096 + cbase + tid]);
        sRf[tid] = m;
    } else {
        int t2 = tid - 128;
        float m = Rsp[cbase + t2];
#pragma unroll
        for (int y = 1; y < 8; ++y) m = fmaxf(m, Rsp[(size_t)y * 4096 + cbase + t2]);
        sRs[t2] = m;
    }

    bf16x8 bres0[8], bres1[8];
#pragma unroll
    for (int kc = 0; kc < 8; ++kc) {
        int koff = kc * 16 + half * 8;
        bres0[kc] = ldfrag(fb, i, koff);
        bres1[kc] = ldfrag(sprb, i, koff);
    }

    float rfi = Rfp[i], rsi = Rsp[i];
#pragma unroll
    for (int y = 1; y < 8; ++y) {
        rfi = fmaxf(rfi, Rfp[(size_t)y * 4096 + i]);
        rsi = fmaxf(rsi, Rsp[(size_t)y * 4096 + i]);
    }
    // one uint4 covers all 128 j of this block's chunk: word s <-> tile s
    uint4 mbts = *(const uint4*)(mnbBits + ((size_t)(i & 255) << 7) + (cbase >> 5));

    __syncthreads();   // sRf/sRs visible; the ONLY barrier in this kernel

    float wsum = 0.f, ones = 0.f, Az = 0.f, Ax = 0.f, Zz = 0.f, Zx = 0.f;
    const float c1 = TEMP_INV * LOG2E;
    u64 bitsv[4];

    // 8 phases: s=0..3 pass0 (f,s_pr masks), s=4..7 pass1 (z,zmix stats)
#pragma unroll
    for (int s = 0; s < 8; ++s) {
        const u16* jm0 = (s < 4) ? fb : zb;
        const u16* jm1 = (s < 4) ? sprb : zmxb;
        int j0 = cbase + (s & 3) * 32;
        if (s == 4) {   // swap residents to z,zmix
#pragma unroll
            for (int kc = 0; kc < 8; ++kc) {
                int koff = kc * 16 + half * 8;
                bres0[kc] = ldfrag(zb, i, koff);
                bres1[kc] = ldfrag(zmxb, i, koff);
            }
        }
        f32x16 acc0 = {}; f32x16 acc1 = {};
        __builtin_amdgcn_s_setprio(1);
#pragma unroll
        for (int kc = 0; kc < 8; ++kc) {
            int koff = kc * 16 + half * 8;
            bf16x8 a0 = ldfrag(jm0, j0 + li, koff);
            bf16x8 a1 = ldfrag(jm1, j0 + li, koff);
            acc0 = __builtin_amdgcn_mfma_f32_32x32x16_bf16(a0, bres0[kc], acc0, 0, 0, 0);
            acc1 = __builtin_amdgcn_mfma_f32_32x32x16_bf16(a1, bres1[kc], acc1, 0, 0, 0);
        }
        __builtin_amdgcn_s_setprio(0);
        // elem r: j = j0 + (r&3) + 8*(r>>2) + 4*half  (m74/m101 C/D layout), col i = lane&31
        if (s < 4) {
            u32 mb = (s == 0) ? mbts.x : (s == 1) ? mbts.y : (s == 2) ? mbts.z : mbts.w;
            u64 bits = 0;
#pragma unroll
            for (int q = 0; q < 4; ++q) {
                int jb = j0 + q * 8 + half * 4;
                f32x4 rf4 = *(const f32x4*)(sRf + (jb - cbase));
                f32x4 rs4 = *(const f32x4*)(sRs + (jb - cbase));
#pragma unroll
                for (int t = 0; t < 4; ++t) {
                    int r = q * 4 + t;
                    int j = jb + t;
                    bool nm = (j != i);
                    bool mob = acc0[r] > fminf(rfi, rf4[t]);
                    bool meb = acc1[r] > fminf(rsi, rs4[t]);
                    bool mnbv = (mb >> (q * 8 + half * 4 + t)) & 1u;   // bit j-j0
                    u32 e = ((mob && nm) ? 1u : 0u) | ((meb && nm) ? 2u : 0u) |
                            (((mob || mnbv) && nm) ? 4u : 0u);
                    bits |= (u64)e << (4 * r);
                }
            }
            bitsv[s] = bits;
        } else {
            u64 bits = bitsv[s - 4];
#pragma unroll
            for (int r = 0; r < 16; ++r) {
                u32 e = (u32)(bits >> (4 * r)) & 7u;
                float w1 = (e & 1u) ? 1.0f : 0.0f;
                float wv = w1 + ((e & 2u) ? 0.5f : 0.0f);
                float ng = (e & 4u) ? 1.0f : 0.0f;
                float lvz = acc0[r], lvx = acc1[r];
                wsum += wv; ones += w1;
                Az = fmaf(wv, lvz, Az);
                Ax = fmaf(wv, lvx, Ax);
                Zz = fmaf(ng, EXP2(fmaf(lvz, c1, -c1)), Zz);
                Zx = fmaf(ng, EXP2(fmaf(lvx, c1, -c1)), Zx);
            }
        }
    }

    // combine two lane-halves (disjoint j sets, same i)
    wsum += __shfl_xor(wsum, 32, 64);
    ones += __shfl_xor(ones, 32, 64);
    Az += __shfl_xor(Az, 32, 64);
    Ax += __shfl_xor(Ax, 32, 64);
    Zz += __shfl_xor(Zz, 32, 64);
    Zx += __shfl_xor(Zx, 32, 64);
    if (half == 0) {
        // deterministic fixed-point atomic accumulation (integer add = order-free)
        u32 cnt = ((u32)(wsum * 2.0f + 0.5f) << 16) | (u32)(ones + 0.5f);
        atomicAdd(CNT + i, cnt);
        atomicAdd(&PA[i],            (u64)(long long)llrintf(Az * SC_A));
        atomicAdd(&PA[4096 + i],     (u64)(long long)llrintf(Ax * SC_A));
        atomicAdd(&PA[2 * 4096 + i], (u64)llrintf(Zz * SC_Z));
        atomicAdd(&PA[3 * 4096 + i], (u64)llrintf(Zx * SC_Z));
    }
}

// ---------------- Kernel 2: per-m block means, ticketed final sum ----------------
__global__ __launch_bounds__(256) void k_final(const u64* __restrict__ PA,
                                               const u32* __restrict__ CNT,
                                               float* __restrict__ accum, u32* __restrict__ ticket,
                                               u32* __restrict__ out) {
    int t = threadIdx.x;
    int i = blockIdx.x * 256 + t;
    u32 cnt = CNT[i];
    float ones = (float)(cnt & 0xFFFFu);
    float wsum = 0.5f * (float)(cnt >> 16);
    long long azi = (long long)PA[i];
    long long axi = (long long)PA[4096 + i];
    long long zzi = (long long)PA[2 * 4096 + i];
    long long zxi = (long long)PA[3 * 4096 + i];
    float Az = (float)((double)azi * ISC_A);
    float Ax = (float)((double)axi * ISC_A);
    float Zz = (float)((double)zzi * ISC_Z);
    float Zx = (float)((double)zxi * ISC_Z);

    float dw = wsum > 0.f ? wsum : 1.0f;
    float lz = Zz > 0.f ? logf(Zz) : 0.f;
    float lx = Zx > 0.f ? logf(Zx) : 0.f;
    float mlz = (TEMP_INV * Az - wsum * (TEMP_INV + lz)) / dw;
    float mlx = (TEMP_INV * Ax - wsum * (TEMP_INV + lx)) / dw;
    float si = ones > 0.f ? wsum : 0.f;
    float ci = (mlz + mlx) * si;
#pragma unroll
    for (int d = 1; d < 64; d <<= 1) {
        ci += __shfl_xor(ci, d, 64);
        si += __shfl_xor(si, d, 64);
    }
    __shared__ float rc[4], rs[4];
    int wv = t >> 6;
    if ((t & 63) == 0) { rc[wv] = ci; rs[wv] = si; }
    __syncthreads();
    if (t == 0) {
        float cs = rc[0] + rc[1] + rc[2] + rc[3];
        float ss = rs[0] + rs[1] + rs[2] + rs[3];
        float ratio = ss > 0.f ? cs / ss : 0.f;
        atomicAdd(accum, ratio);
        __threadfence();
        u32 old = atomicAdd(ticket, 1u);
        if (old == 15u) {
            float total = atomicAdd(accum, 0.0f);  // all 16 adds complete
            __hip_bfloat16 hb = __float2bfloat16(-total / 32.0f);
            u32 bits = (u32)__bfloat16_as_ushort(hb);
            out[0] = (bits << 16) | bits;  // bf16/f32 dual-interpretation hedge
        }
    }
}

extern "C" void kernel_launch(void* const* d_in, const int* in_sizes, int n_in,
                              void* d_out, int out_size, void* d_ws, size_t ws_size,
                              hipStream_t stream) {
    const float* z   = (const float*)d_in[0];
    const float* spr = (const float*)d_in[1];
    const float* f   = (const float*)d_in[2];
    const float* pag = (const float*)d_in[3];
    const float* psp = (const float*)d_in[4];
    const float* zmx = (const float*)d_in[5];
    const float* mnb = (const float*)d_in[6];

    u16* cb      = (u16*)((char*)d_ws + CB_OFF);
    float* Rfp   = (float*)((char*)d_ws + RF_OFF);
    float* Rsp   = (float*)((char*)d_ws + RS_OFF);
    u64* PA      = (u64*)((char*)d_ws + PACC_OFF);
    u32* CNT     = (u32*)((char*)d_ws + CNT_OFF);
    float* accum = (float*)((char*)d_ws + AT_OFF);
    u32* ticket  = (u32*)((char*)d_ws + AT_OFF + 4);
    u32* mnbBits = (u32*)((char*)d_ws + MNB_OFF);

    k_prep<<<PREP_BLKS, 256, 0, stream>>>(z, spr, f, pag, psp, zmx, mnb, cb, mnbBits, Rfp, Rsp, PA);
    k_main<<<dim3(32, 32), 256, 0, stream>>>(cb, mnbBits, Rfp, Rsp, PA, CNT);
    k_final<<<16, 256, 0, stream>>>(PA, CNT, accum, ticket, (u32*)d_out);
}

// Round 9
// 144.410 us; speedup vs baseline: 1.1612x; 1.1612x over previous
//
#include <hip/hip_runtime.h>
#include <hip/hip_bf16.h>

typedef unsigned short u16;
typedef unsigned int u32;
typedef unsigned long long u64;
typedef __bf16 bf16x8 __attribute__((ext_vector_type(8)));
typedef unsigned short u16x8 __attribute__((ext_vector_type(8)));
typedef float f32x16 __attribute__((ext_vector_type(16)));
typedef float f32x4 __attribute__((ext_vector_type(4)));

#define TEMP_INV (1.0f / 0.07f)
#define LOG2E 1.4426950408889634f
#define SC_A  1099511627776.0f        // 2^40 (power of 2: f32 multiply exact)
#define ISC_A 9.094947017729282e-13   // 2^-40
#define SC_Z  1125899906842624.0f     // 2^50
#define ISC_Z 8.881784197001252e-16   // 2^-50

#if __has_builtin(__builtin_amdgcn_exp2f)
#define EXP2(x) __builtin_amdgcn_exp2f(x)
#else
#define EXP2(x) exp2f(x)
#endif

// async 16B global->LDS DMA: per-lane global src, wave-uniform LDS base (+lane*16 implicit)
#define GLOAD_LDS16(g, l) __builtin_amdgcn_global_load_lds( \
    (const __attribute__((address_space(1))) unsigned int*)(g), \
    (__attribute__((address_space(3))) unsigned int*)(l), 16, 0, 0)

#define N_Z 524288      // 4096*128

// ---- workspace layout (4.74 MB) ----
// cb: bf16 z|spr|f|zmix, XOR-SWIZZLED in 16B units (u ^= row&7) -- written by prep
// Rfp[8][4096] | Rsp[8][4096] f32 partial pool maxes (plain stores)
// PA u64[4][4096] (Az,Ax i64*2^40; Zz,Zx u64*2^50)  -- zeroed by prep
// CNT u32[4096]  ((2*wsum)<<16 | ones)              -- zeroed by prep
// accum f32 + ticket u32 + pad                       -- zeroed by prep
// mnbBits[256][128] u32 (fully rewritten each iter)
#define CB_OFF   0
#define RF_OFF   4194304
#define RS_OFF   4325376
#define PACC_OFF 4456448
#define CNT_OFF  4587520
#define AT_OFF   4603904
#define MNB_OFF  4603920
#define ZERO_UNITS 9217   // (PA 131072 + CNT 16384 + AT 16) / 16

// k_prep block ranges
#define PM_BLKS 256
#define CONV0 PM_BLKS                   // 256
#define CONV_BLKS 2048
#define MNB0 (CONV0 + CONV_BLKS)        // 2304
#define MNB_BLKS 256
#define ZERO0 (MNB0 + MNB_BLKS)         // 2560
#define ZERO_BLKS 37
#define PREP_BLKS (ZERO0 + ZERO_BLKS)   // 2597

// LDS tile for prep poolmax only (padded-stride layout, register-staged)
#define TSTRIDE 136
#define TMAT 4352   // 32*136 u16 per mat

// load 8 f32, convert to bf16x8 (RNE — matches the convert path bit-exactly)
__device__ __forceinline__ bf16x8 ldcvt8(const float* __restrict__ p) {
    f32x4 a = *(const f32x4*)p;
    f32x4 b = *(const f32x4*)(p + 4);
    u16x8 t;
    t[0] = __bfloat16_as_ushort(__float2bfloat16(a[0]));
    t[1] = __bfloat16_as_ushort(__float2bfloat16(a[1]));
    t[2] = __bfloat16_as_ushort(__float2bfloat16(a[2]));
    t[3] = __bfloat16_as_ushort(__float2bfloat16(a[3]));
    t[4] = __bfloat16_as_ushort(__float2bfloat16(b[0]));
    t[5] = __bfloat16_as_ushort(__float2bfloat16(b[1]));
    t[6] = __bfloat16_as_ushort(__float2bfloat16(b[2]));
    t[7] = __bfloat16_as_ushort(__float2bfloat16(b[3]));
    return __builtin_bit_cast(bf16x8, t);
}

// swizzled-cb fragment load: logical (row, 16B-unit uc) -> unit (uc ^ (row&7))
__device__ __forceinline__ bf16x8 ldfrag_swz(const u16* __restrict__ base, int row, int uc) {
    return *(const bf16x8*)(base + (size_t)row * 128 + (size_t)((uc ^ (row & 7)) << 3));
}

// ---------------- Kernel 0: prep ----------------
// [0,256): pool partial maxes (f32 inputs, inline cvt, plain partial stores)
// [256,2304): f32->bf16 convert of z,spr,f,zmix into SWIZZLED cb
// [2304,2560): mnb bit-pack (1 row per block)
// [2560,2597): zero PA/CNT/accum/ticket
__global__ __launch_bounds__(256) void k_prep(
    const float* __restrict__ z, const float* __restrict__ spr,
    const float* __restrict__ f, const float* __restrict__ pag,
    const float* __restrict__ psp, const float* __restrict__ zmx,
    const float* __restrict__ mnb,
    u16* __restrict__ cb, u32* __restrict__ mnbBits,
    float* __restrict__ Rfp, float* __restrict__ Rsp, u64* __restrict__ PA) {
    __shared__ u16 stile[2][2 * TMAT];
    int b = blockIdx.x;
    int tid = threadIdx.x;

    if (b < PM_BLKS) {
        int x = b & 31, y = b >> 5;
        int lane = tid & 63, w = tid >> 6;
        int half = lane >> 5, li = lane & 31;
        int i = x * 128 + w * 32 + li;
        int pybase = y * 128;
        int srow = tid >> 4, sc16 = tid & 15;

        bf16x8 brf[8], brs[8];
#pragma unroll
        for (int kc = 0; kc < 8; ++kc) {
            int koff = kc * 16 + half * 8;
            brf[kc] = ldcvt8(f + (size_t)i * 128 + koff);
            brs[kc] = ldcvt8(spr + (size_t)i * 128 + koff);
        }

        bf16x8 q00, q01, q10, q11;
        {   // tile 0 -> buf0
            const float* pr = pag + (size_t)(pybase + srow) * 128 + sc16 * 8;
            const float* ps = psp + (size_t)(pybase + srow) * 128 + sc16 * 8;
            q00 = ldcvt8(pr); q01 = ldcvt8(pr + 16 * 128);
            q10 = ldcvt8(ps); q11 = ldcvt8(ps + 16 * 128);
            u16* tb = stile[0];
            *(bf16x8*)(tb + (size_t)srow * TSTRIDE + sc16 * 8) = q00;
            *(bf16x8*)(tb + (size_t)(srow + 16) * TSTRIDE + sc16 * 8) = q01;
            *(bf16x8*)(tb + TMAT + (size_t)srow * TSTRIDE + sc16 * 8) = q10;
            *(bf16x8*)(tb + TMAT + (size_t)(srow + 16) * TSTRIDE + sc16 * 8) = q11;
        }
        {   // prefetch tile 1
            const float* pr = pag + (size_t)(pybase + 32 + srow) * 128 + sc16 * 8;
            const float* ps = psp + (size_t)(pybase + 32 + srow) * 128 + sc16 * 8;
            q00 = ldcvt8(pr); q01 = ldcvt8(pr + 16 * 128);
            q10 = ldcvt8(ps); q11 = ldcvt8(ps + 16 * 128);
        }

        float rmf = -1e30f, rms = -1e30f;
#pragma unroll
        for (int t = 0; t < 4; ++t) {
            __syncthreads();
            if (t < 3) {
                u16* tb = stile[(t + 1) & 1];
                *(bf16x8*)(tb + (size_t)srow * TSTRIDE + sc16 * 8) = q00;
                *(bf16x8*)(tb + (size_t)(srow + 16) * TSTRIDE + sc16 * 8) = q01;
                *(bf16x8*)(tb + TMAT + (size_t)srow * TSTRIDE + sc16 * 8) = q10;
                *(bf16x8*)(tb + TMAT + (size_t)(srow + 16) * TSTRIDE + sc16 * 8) = q11;
                if (t < 2) {
                    const float* pr = pag + (size_t)(pybase + (t + 2) * 32 + srow) * 128 + sc16 * 8;
                    const float* ps = psp + (size_t)(pybase + (t + 2) * 32 + srow) * 128 + sc16 * 8;
                    q00 = ldcvt8(pr); q01 = ldcvt8(pr + 16 * 128);
                    q10 = ldcvt8(ps); q11 = ldcvt8(ps + 16 * 128);
                }
            }
            const u16* tb = stile[t & 1];
            f32x16 accf = {}; f32x16 accs = {};
            __builtin_amdgcn_s_setprio(1);
#pragma unroll
            for (int kc = 0; kc < 8; ++kc) {
                const u16* ab = tb + li * TSTRIDE + kc * 16 + half * 8;
                bf16x8 a0 = *(const bf16x8*)ab;
                bf16x8 a1 = *(const bf16x8*)(ab + TMAT);
                accf = __builtin_amdgcn_mfma_f32_32x32x16_bf16(a0, brf[kc], accf, 0, 0, 0);
                accs = __builtin_amdgcn_mfma_f32_32x32x16_bf16(a1, brs[kc], accs, 0, 0, 0);
            }
            __builtin_amdgcn_s_setprio(0);
#pragma unroll
            for (int r = 0; r < 16; ++r) {
                rmf = fmaxf(rmf, accf[r]);
                rms = fmaxf(rms, accs[r]);
            }
        }
        rmf = fmaxf(rmf, __shfl_xor(rmf, 32, 64));
        rms = fmaxf(rms, __shfl_xor(rms, 32, 64));
        if (half == 0) {
            Rfp[(size_t)y * 4096 + i] = rmf;
            Rsp[(size_t)y * 4096 + i] = rms;
        }
        return;
    }
    if (b < MNB0) {
        // convert z,spr,f,zmix f32->bf16 into cb at SWIZZLED position (16B-unit u ^= row&7)
        size_t e0 = ((size_t)(b - CONV0) * 256 + tid) * 4;
        const float* src; size_t off; int mi;
        if (e0 < N_Z)          { src = z;   off = e0;           mi = 0; }
        else if (e0 < 2 * N_Z) { src = spr; off = e0 - N_Z;     mi = 1; }
        else if (e0 < 3 * N_Z) { src = f;   off = e0 - 2 * N_Z; mi = 2; }
        else                   { src = zmx; off = e0 - 3 * N_Z; mi = 3; }
        f32x4 v = *(const f32x4*)(src + off);
        ushort4 o;
        o.x = __bfloat16_as_ushort(__float2bfloat16(v[0]));
        o.y = __bfloat16_as_ushort(__float2bfloat16(v[1]));
        o.z = __bfloat16_as_ushort(__float2bfloat16(v[2]));
        o.w = __bfloat16_as_ushort(__float2bfloat16(v[3]));
        int row = (int)(off >> 7), col = (int)(off & 127);
        size_t dsto = (size_t)mi * N_Z + (size_t)row * 128 +
                      (size_t)((((col >> 3) ^ (row & 7)) << 3) + (col & 7));
        *(ushort4*)(cb + dsto) = o;
        return;
    }
    if (b < ZERO0) {
        // pack mnb row: [4096] f32 -> 64 u64 words; bit l of word w <-> j = w*64+l
        int row = b - MNB0;
        int wv = tid >> 6, l = tid & 63;
        const float* srcm = mnb + (size_t)row * 4096;
        u64* db = (u64*)mnbBits + ((size_t)row << 6);
#pragma unroll
        for (int t = 0; t < 16; ++t) {
            int word = wv * 16 + t;
            u64 m = __ballot(srcm[word * 64 + l] > 0.0f);
            if (l == t) db[word] = m;
        }
        return;
    }
    {   // zero PA / CNT / accum / ticket
        int u = (b - ZERO0) * 256 + tid;
        if (u < ZERO_UNITS) {
            uint4 zero = {0, 0, 0, 0};
            *(uint4*)((char*)PA + (size_t)u * 16) = zero;
        }
    }
}

// wave-cooperative DMA stage of one 32-row j-tile (2 mats, 16KB) into dstbuf.
// cb is pre-swizzled; linear LDS copy preserves the swizzle; ds_reads apply the XOR.
__device__ __forceinline__ void stage_tile(const u16* __restrict__ m0,
                                           const u16* __restrict__ m1,
                                           int j0, u16* dstbuf, int w, int lane) {
#pragma unroll
    for (int t = 0; t < 4; ++t) {
        int bn = (w * 4 + t) * 64;        // wave-uniform base 16B-unit
        int n = bn + lane;                // this lane's unit (lane offset applied by HW)
        int mat = n >> 9, r = (n >> 4) & 31, u = n & 15;
        const u16* src = (mat ? m1 : m0) +
                         (size_t)(j0 + r) * 128 + (size_t)((u ^ (r & 7)) << 3);
        GLOAD_LDS16(src, dstbuf + (size_t)bn * 8);
    }
}

// ---------------- Kernel 1: main fused two-pass kernel ----------------
// grid (32, 32): 128 i per block, 128-j chunk. LDS j-tiles staged via global_load_lds
// DMA (double-buffered, ONE barrier per tile, loads fly under MFMA+epilogue).
// Fixed-point atomic accumulation of the 6 per-i stats (order-free, proven exact).
__global__ __launch_bounds__(256) void k_main(
    const u16* __restrict__ cb, const u32* __restrict__ mnbBits,
    const float* __restrict__ Rfp, const float* __restrict__ Rsp,
    u64* __restrict__ PA, u32* __restrict__ CNT) {
    __shared__ u16 stile[2][8192];   // 2 x 16KB linear (swizzled content)
    __shared__ float sRf[128], sRs[128];

    const u16* zb   = cb;
    const u16* sprb = cb + N_Z;
    const u16* fb   = cb + 2 * N_Z;
    const u16* zmxb = cb + 3 * N_Z;

    int tid = threadIdx.x;
    int lane = tid & 63, w = tid >> 6;
    int half = lane >> 5, li = lane & 31;
    int i = blockIdx.x * 128 + w * 32 + li;
    int cbase = blockIdx.y * 128;

    // kick tile-0 DMA immediately; its latency hides under the whole prologue
    stage_tile(fb, sprb, cbase, stile[0], w, lane);

    // chunk's pool maxes: 8-way partial max into LDS (broadcast reads later)
    if (tid < 128) {
        float m = Rfp[cbase + tid];
#pragma unroll
        for (int y = 1; y < 8; ++y) m = fmaxf(m, Rfp[(size_t)y * 4096 + cbase + tid]);
        sRf[tid] = m;
    } else {
        int t2 = tid - 128;
        float m = Rsp[cbase + t2];
#pragma unroll
        for (int y = 1; y < 8; ++y) m = fmaxf(m, Rsp[(size_t)y * 4096 + cbase + t2]);
        sRs[t2] = m;
    }

    bf16x8 bres0[8], bres1[8];
#pragma unroll
    for (int kc = 0; kc < 8; ++kc) {
        int uc = kc * 2 + half;
        bres0[kc] = ldfrag_swz(fb, i, uc);
        bres1[kc] = ldfrag_swz(sprb, i, uc);
    }

    float rfi = Rfp[i], rsi = Rsp[i];
#pragma unroll
    for (int y = 1; y < 8; ++y) {
        rfi = fmaxf(rfi, Rfp[(size_t)y * 4096 + i]);
        rsi = fmaxf(rsi, Rsp[(size_t)y * 4096 + i]);
    }
    // one uint4 covers all 128 j of this block's chunk: word s <-> tile s
    uint4 mbts = *(const uint4*)(mnbBits + ((size_t)(i & 255) << 7) + (cbase >> 5));

    asm volatile("s_waitcnt vmcnt(0)" ::: "memory");   // tile-0 DMA landed
    __syncthreads();                                   // + sRf/sRs visible

    float wsum = 0.f, ones = 0.f, Az = 0.f, Ax = 0.f, Zz = 0.f, Zx = 0.f;
    const float c1 = TEMP_INV * LOG2E;
    u64 bitsv[4];
    int sw = li & 7;

    // 8 tiles: s=0..3 pass0 (f,s_pr masks), s=4..7 pass1 (z,zmix stats)
#pragma unroll
    for (int s = 0; s < 8; ++s) {
        if (s < 7) {   // DMA next tile into the other buffer; flies under compute
            int t = s + 1;
            stage_tile(t < 4 ? fb : zb, t < 4 ? sprb : zmxb,
                       cbase + (t & 3) * 32, stile[t & 1], w, lane);
        }
        if (s == 4) {   // swap residents to z,zmix (pass-0 MFMAs all consumed)
#pragma unroll
            for (int kc = 0; kc < 8; ++kc) {
                int uc = kc * 2 + half;
                bres0[kc] = ldfrag_swz(zb, i, uc);
                bres1[kc] = ldfrag_swz(zmxb, i, uc);
            }
        }
        const u16* tb = stile[s & 1];
        f32x16 acc0 = {}; f32x16 acc1 = {};
        __builtin_amdgcn_s_setprio(1);
#pragma unroll
        for (int kc = 0; kc < 8; ++kc) {
            int c = kc * 2 + half;
            const u16* ab = tb + (size_t)((li * 16 + (c ^ sw)) << 3);
            bf16x8 a0 = *(const bf16x8*)ab;
            bf16x8 a1 = *(const bf16x8*)(ab + 4096);   // mat1 = +512 units = +4096 u16
            acc0 = __builtin_amdgcn_mfma_f32_32x32x16_bf16(a0, bres0[kc], acc0, 0, 0, 0);
            acc1 = __builtin_amdgcn_mfma_f32_32x32x16_bf16(a1, bres1[kc], acc1, 0, 0, 0);
        }
        __builtin_amdgcn_s_setprio(0);
        // elem r: j = j0 + (r&3) + 8*(r>>2) + 4*half  (m74/m101 C/D layout), col i = lane&31
        if (s < 4) {
            int j0 = cbase + s * 32;
            u32 mb = (s == 0) ? mbts.x : (s == 1) ? mbts.y : (s == 2) ? mbts.z : mbts.w;
            u64 bits = 0;
#pragma unroll
            for (int q = 0; q < 4; ++q) {
                int jb = j0 + q * 8 + half * 4;
                f32x4 rf4 = *(const f32x4*)(sRf + (jb - cbase));
                f32x4 rs4 = *(const f32x4*)(sRs + (jb - cbase));
#pragma unroll
                for (int t = 0; t < 4; ++t) {
                    int r = q * 4 + t;
                    int j = jb + t;
                    bool nm = (j != i);
                    bool mob = acc0[r] > fminf(rfi, rf4[t]);
                    bool meb = acc1[r] > fminf(rsi, rs4[t]);
                    bool mnbv = (mb >> (q * 8 + half * 4 + t)) & 1u;   // bit j-j0
                    u32 e = ((mob && nm) ? 1u : 0u) | ((meb && nm) ? 2u : 0u) |
                            (((mob || mnbv) && nm) ? 4u : 0u);
                    bits |= (u64)e << (4 * r);
                }
            }
            bitsv[s] = bits;
        } else {
            u64 bits = bitsv[s - 4];
#pragma unroll
            for (int r = 0; r < 16; ++r) {
                u32 e = (u32)(bits >> (4 * r)) & 7u;
                float w1 = (e & 1u) ? 1.0f : 0.0f;
                float wv = w1 + ((e & 2u) ? 0.5f : 0.0f);
                float ng = (e & 4u) ? 1.0f : 0.0f;
                float lvz = acc0[r], lvx = acc1[r];
                wsum += wv; ones += w1;
                Az = fmaf(wv, lvz, Az);
                Ax = fmaf(wv, lvx, Ax);
                Zz = fmaf(ng, EXP2(fmaf(lvz, c1, -c1)), Zz);
                Zx = fmaf(ng, EXP2(fmaf(lvx, c1, -c1)), Zx);
            }
        }
        if (s < 7) {
            asm volatile("s_waitcnt vmcnt(0)" ::: "memory");   // next tile's DMA done
            __syncthreads();                                   // all waves done with buf[s&1]
        }
    }

    // combine two lane-halves (disjoint j sets, same i)
    wsum += __shfl_xor(wsum, 32, 64);
    ones += __shfl_xor(ones, 32, 64);
    Az += __shfl_xor(Az, 32, 64);
    Ax += __shfl_xor(Ax, 32, 64);
    Zz += __shfl_xor(Zz, 32, 64);
    Zx += __shfl_xor(Zx, 32, 64);
    if (half == 0) {
        // deterministic fixed-point atomic accumulation (integer add = order-free)
        u32 cnt = ((u32)(wsum * 2.0f + 0.5f) << 16) | (u32)(ones + 0.5f);
        atomicAdd(CNT + i, cnt);
        atomicAdd(&PA[i],            (u64)(long long)llrintf(Az * SC_A));
        atomicAdd(&PA[4096 + i],     (u64)(long long)llrintf(Ax * SC_A));
        atomicAdd(&PA[2 * 4096 + i], (u64)llrintf(Zz * SC_Z));
        atomicAdd(&PA[3 * 4096 + i], (u64)llrintf(Zx * SC_Z));
    }
}

// ---------------- Kernel 2: per-m block means, ticketed final sum ----------------
__global__ __launch_bounds__(256) void k_final(const u64* __restrict__ PA,
                                               const u32* __restrict__ CNT,
                                               float* __restrict__ accum, u32* __restrict__ ticket,
                                               u32* __restrict__ out) {
    int t = threadIdx.x;
    int i = blockIdx.x * 256 + t;
    u32 cnt = CNT[i];
    float ones = (float)(cnt & 0xFFFFu);
    float wsum = 0.5f * (float)(cnt >> 16);
    long long azi = (long long)PA[i];
    long long axi = (long long)PA[4096 + i];
    long long zzi = (long long)PA[2 * 4096 + i];
    long long zxi = (long long)PA[3 * 4096 + i];
    float Az = (float)((double)azi * ISC_A);
    float Ax = (float)((double)axi * ISC_A);
    float Zz = (float)((double)zzi * ISC_Z);
    float Zx = (float)((double)zxi * ISC_Z);

    float dw = wsum > 0.f ? wsum : 1.0f;
    float lz = Zz > 0.f ? logf(Zz) : 0.f;
    float lx = Zx > 0.f ? logf(Zx) : 0.f;
    float mlz = (TEMP_INV * Az - wsum * (TEMP_INV + lz)) / dw;
    float mlx = (TEMP_INV * Ax - wsum * (TEMP_INV + lx)) / dw;
    float si = ones > 0.f ? wsum : 0.f;
    float ci = (mlz + mlx) * si;
#pragma unroll
    for (int d = 1; d < 64; d <<= 1) {
        ci += __shfl_xor(ci, d, 64);
        si += __shfl_xor(si, d, 64);
    }
    __shared__ float rc[4], rs[4];
    int wv = t >> 6;
    if ((t & 63) == 0) { rc[wv] = ci; rs[wv] = si; }
    __syncthreads();
    if (t == 0) {
        float cs = rc[0] + rc[1] + rc[2] + rc[3];
        float ss = rs[0] + rs[1] + rs[2] + rs[3];
        float ratio = ss > 0.f ? cs / ss : 0.f;
        atomicAdd(accum, ratio);
        __threadfence();
        u32 old = atomicAdd(ticket, 1u);
        if (old == 15u) {
            float total = atomicAdd(accum, 0.0f);  // all 16 adds complete
            __hip_bfloat16 hb = __float2bfloat16(-total / 32.0f);
            u32 bits = (u32)__bfloat16_as_ushort(hb);
            out[0] = (bits << 16) | bits;  // bf16/f32 dual-interpretation hedge
        }
    }
}

extern "C" void kernel_launch(void* const* d_in, const int* in_sizes, int n_in,
                              void* d_out, int out_size, void* d_ws, size_t ws_size,
                              hipStream_t stream) {
    const float* z   = (const float*)d_in[0];
    const float* spr = (const float*)d_in[1];
    const float* f   = (const float*)d_in[2];
    const float* pag = (const float*)d_in[3];
    const float* psp = (const float*)d_in[4];
    const float* zmx = (const float*)d_in[5];
    const float* mnb = (const float*)d_in[6];

    u16* cb      = (u16*)((char*)d_ws + CB_OFF);
    float* Rfp   = (float*)((char*)d_ws + RF_OFF);
    float* Rsp   = (float*)((char*)d_ws + RS_OFF);
    u64* PA      = (u64*)((char*)d_ws + PACC_OFF);
    u32* CNT     = (u32*)((char*)d_ws + CNT_OFF);
    float* accum = (float*)((char*)d_ws + AT_OFF);
    u32* ticket  = (u32*)((char*)d_ws + AT_OFF + 4);
    u32* mnbBits = (u32*)((char*)d_ws + MNB_OFF);

    k_prep<<<PREP_BLKS, 256, 0, stream>>>(z, spr, f, pag, psp, zmx, mnb, cb, mnbBits, Rfp, Rsp, PA);
    k_main<<<dim3(32, 32), 256, 0, stream>>>(cb, mnbBits, Rfp, Rsp, PA, CNT);
    k_final<<<16, 256, 0, stream>>>(PA, CNT, accum, ticket, (u32*)d_out);
}